// Round 4
// baseline (1613.238 us; speedup 1.0000x reference)
//
#include <hip/hip_runtime.h>

// RelGraphConv basis-decomposition forward, MI355X.
//
// Input-space reformulation:
//   g[d, b, :] = sum_{e: dst_e = d} w_comp[et_e, b] * feat[src_e, :]   (b = 0,1)
//   out[d]     = g[d,0] @ V0 + g[d,1] @ V1 + feat[d] @ W_loop + bias
//
// Pipeline:
//   memset bcnt -> k_bhist -> k_bscan -> k_bscatter (coarse 391-bucket
//   multisplit, packed u32 entries) -> k_agg (one block per bucket, 256x128
//   f32 accumulator in 128KB LDS, ds_add_f32) -> k_post (dense 192->64).

constexpr int N_NODES  = 100000;
constexpr int N_EDGES  = 1600000;
constexpr int IN_FEAT  = 64;
constexpr int OUT_FEAT = 64;

constexpr int BN = 256;                                // nodes per bucket
constexpr int NB = (N_NODES + BN - 1) / BN;            // 391 buckets
constexpr int SC_CHUNK = 8192;                         // edges per scatter block

// entry pack: dst_low(8) | src(17) | etype(6)  = 31 bits
__device__ __forceinline__ unsigned pack_entry(int d, int s, int r) {
    return (unsigned)(d & (BN - 1)) | ((unsigned)s << 8) | ((unsigned)r << 25);
}

// ---------------------------------------------------------------- bucket hist
__global__ __launch_bounds__(256) void k_bhist(const int* __restrict__ dst,
                                               int* __restrict__ bcnt) {
    __shared__ int hist[NB];
    const int t = threadIdx.x;
    for (int i = t; i < NB; i += 256) hist[i] = 0;
    __syncthreads();
    const int cbase = blockIdx.x * 2048;
    #pragma unroll
    for (int k = 0; k < 8; ++k) {
        const int e = cbase + k * 256 + t;
        if (e < N_EDGES) atomicAdd(&hist[dst[e] >> 8], 1);
    }
    __syncthreads();
    for (int i = t; i < NB; i += 256)
        if (hist[i]) atomicAdd(&bcnt[i], hist[i]);
}

// ---------------------------------------------------------------- bucket scan
__global__ __launch_bounds__(512) void k_bscan(const int* __restrict__ bcnt,
                                               int* __restrict__ bbase,
                                               int* __restrict__ bcursor) {
    __shared__ int part[512];
    const int t = threadIdx.x;
    const int v = (t < NB) ? bcnt[t] : 0;
    part[t] = v;
    __syncthreads();
    for (int d = 1; d < 512; d <<= 1) {
        const int u = (t >= d) ? part[t - d] : 0;
        __syncthreads();
        part[t] += u;
        __syncthreads();
    }
    if (t < NB) {
        const int ex = part[t] - v;   // exclusive
        bbase[t] = ex;
        bcursor[t] = ex;
    }
    if (t == 0) bbase[NB] = N_EDGES;
}

// ---------------------------------------------------------------- multisplit
__global__ __launch_bounds__(256) void k_bscatter(const int* __restrict__ src,
                                                  const int* __restrict__ dst,
                                                  const int* __restrict__ et,
                                                  int* __restrict__ bcursor,
                                                  unsigned* __restrict__ sorted) {
    __shared__ int hist[NB], gb[NB], lcur[NB];
    const int t = threadIdx.x;
    const int cbase = blockIdx.x * SC_CHUNK;
    for (int i = t; i < NB; i += 256) { hist[i] = 0; lcur[i] = 0; }
    __syncthreads();
    #pragma unroll 1
    for (int k = 0; k < SC_CHUNK / 256; ++k) {
        const int e = cbase + k * 256 + t;
        if (e < N_EDGES) atomicAdd(&hist[dst[e] >> 8], 1);
    }
    __syncthreads();
    for (int i = t; i < NB; i += 256) {
        const int c = hist[i];
        gb[i] = c ? atomicAdd(&bcursor[i], c) : 0;
    }
    __syncthreads();
    #pragma unroll 1
    for (int k = 0; k < SC_CHUNK / 256; ++k) {
        const int e = cbase + k * 256 + t;
        if (e < N_EDGES) {
            const int d = dst[e];
            const int bkt = d >> 8;
            const unsigned entry = pack_entry(d, src[e], et[e]);
            const int r = atomicAdd(&lcur[bkt], 1);
            sorted[gb[bkt] + r] = entry;   // ~21-entry runs per (block,bucket)
        }
    }
}

// ---------------------------------------------------------------- aggregate
// One block per bucket; 256-node x 128-feature f32 accumulator in 128KB LDS.
// Per edge: 256B coalesced feat read (lane = feature), two ds_add_f32.
__global__ __launch_bounds__(512, 1) void k_agg(
    const unsigned* __restrict__ sorted,
    const int*      __restrict__ bbase,
    const float*    __restrict__ feat,     // (N, 64)
    const float*    __restrict__ w_comp,   // (64, 2)
    float*          __restrict__ g_glob)   // (N, 128): [0..63]=b0, [64..127]=b1
{
    __shared__ float g[BN * 128];          // 128 KB
    const int t = threadIdx.x, lane = t & 63, w = t >> 6;
    const int b = blockIdx.x;

    #pragma unroll
    for (int k = 0; k < BN * 128 / 512; ++k) g[k * 512 + t] = 0.0f;
    __syncthreads();

    const int base = bbase[b];
    const int end  = bbase[b + 1];
    const float2* __restrict__ wc = (const float2*)w_comp;

    for (int span = base + w * 64; span < end; span += 512) {
        const int navail = end - span;
        const unsigned ev = sorted[span + (lane < navail ? lane : navail - 1)];
        const int m = navail < 64 ? navail : 64;
        if (m == 64) {
            #pragma unroll 1
            for (int j0 = 0; j0 < 64; j0 += 8) {
                float f[8]; unsigned en[8];
                #pragma unroll
                for (int k = 0; k < 8; ++k) {
                    en[k] = __shfl(ev, j0 + k);
                    f[k] = feat[(size_t)((en[k] >> 8) & 0x1FFFF) * 64 + lane];
                }
                #pragma unroll
                for (int k = 0; k < 8; ++k) {
                    const float2 c = wc[en[k] >> 25];
                    const int dl = (int)(en[k] & (BN - 1)) * 128;
                    atomicAdd(&g[dl + lane],      c.x * f[k]);
                    atomicAdd(&g[dl + 64 + lane], c.y * f[k]);
                }
            }
        } else {
            for (int j = 0; j < m; ++j) {
                const unsigned e0 = __shfl(ev, j);
                const float f0 = feat[(size_t)((e0 >> 8) & 0x1FFFF) * 64 + lane];
                const float2 c = wc[e0 >> 25];
                const int dl = (int)(e0 & (BN - 1)) * 128;
                atomicAdd(&g[dl + lane],      c.x * f0);
                atomicAdd(&g[dl + 64 + lane], c.y * f0);
            }
        }
    }
    __syncthreads();

    // write bucket's accumulator (coalesced float4); last bucket: 160 nodes
    float4* __restrict__ g4o = (float4*)(g_glob + (size_t)b * BN * 128);
    const float4* g4 = (const float4*)g;
    const int nvalid = (b == NB - 1) ? (N_NODES - b * BN) : BN;
    const int maxf4 = nvalid * 32;
    for (int k = t; k < maxf4; k += 512) g4o[k] = g4[k];
}

// ---------------------------------------------------------------- post GEMM
// out[n, col] = g0[n]@V0[:,col] + g1[n]@V1[:,col] + feat[n]@loop[:,col] + bias.
// 3 waves/block: wave seg in {0,1,2} owns one 64-dim segment, weight column
// in 64 VGPRs; inputs staged per 8-node tile; partials combined via LDS.
__global__ __launch_bounds__(192) void k_post(
    const float* __restrict__ g_glob,      // (N, 128)
    const float* __restrict__ feat,        // (N, 64)
    const float* __restrict__ weight,      // (2, 64, 64)
    const float* __restrict__ loop_weight, // (64, 64)
    const float* __restrict__ h_bias,      // (64,)
    float* __restrict__ out)               // (N, 64)
{
    __shared__ float Lin[8][192];          // [node][0..127]=g, [128..191]=feat
    __shared__ float ps[3][8][64];
    const int tid = threadIdx.x;
    const int col = tid & 63;
    const int seg = tid >> 6;              // wave-uniform

    float wcol[64];
    #pragma unroll
    for (int i = 0; i < 64; ++i) {
        if (seg < 2) wcol[i] = weight[seg * (IN_FEAT * OUT_FEAT) + i * OUT_FEAT + col];
        else         wcol[i] = loop_weight[i * OUT_FEAT + col];
    }

    for (int base = blockIdx.x * 8; base < N_NODES; base += gridDim.x * 8) {
        __syncthreads();   // protect Lin + ps reuse
        for (int idx = tid; idx < 8 * 128; idx += 192) {
            const int j = idx >> 7, i = idx & 127, n = base + j;
            Lin[j][i] = (n < N_NODES) ? g_glob[(size_t)n * 128 + i] : 0.0f;
        }
        for (int idx = tid; idx < 8 * 64; idx += 192) {
            const int j = idx >> 6, i = idx & 63, n = base + j;
            Lin[j][128 + i] = (n < N_NODES) ? feat[(size_t)n * 64 + i] : 0.0f;
        }
        __syncthreads();
        #pragma unroll 1
        for (int j = 0; j < 8; ++j) {
            const float4* v4 = (const float4*)&Lin[j][seg * 64];
            float a0 = 0.f, a1 = 0.f, a2 = 0.f, a3 = 0.f;
            #pragma unroll
            for (int i4 = 0; i4 < 16; ++i4) {
                const float4 f = v4[i4];   // wave-uniform -> LDS broadcast
                a0 = fmaf(f.x, wcol[4 * i4 + 0], a0);
                a1 = fmaf(f.y, wcol[4 * i4 + 1], a1);
                a2 = fmaf(f.z, wcol[4 * i4 + 2], a2);
                a3 = fmaf(f.w, wcol[4 * i4 + 3], a3);
            }
            ps[seg][j][col] = (a0 + a1) + (a2 + a3);
        }
        __syncthreads();
        for (int o = tid; o < 512; o += 192) {
            const int j = o >> 6, c = o & 63, n = base + j;
            if (n < N_NODES)
                out[(size_t)n * 64 + c] = ps[0][j][c] + ps[1][j][c] + ps[2][j][c] + h_bias[c];
        }
    }
}

// ---------------------------------------------------------------- launch
extern "C" void kernel_launch(void* const* d_in, const int* in_sizes, int n_in,
                              void* d_out, int out_size, void* d_ws, size_t ws_size,
                              hipStream_t stream) {
    const float* feat        = (const float*)d_in[0];
    const float* weight      = (const float*)d_in[1];
    const float* w_comp      = (const float*)d_in[2];
    const float* loop_weight = (const float*)d_in[3];
    const float* h_bias      = (const float*)d_in[4];
    const int*   src         = (const int*)d_in[5];
    const int*   dst         = (const int*)d_in[6];
    const int*   etypes      = (const int*)d_in[7];
    float* out = (float*)d_out;

    // ws layout (4B units): g_glob | sorted | bcnt | bbase | bcursor  = ~57.7MB
    float*    g_glob  = (float*)d_ws;                        // N*128 = 12.8M f32
    unsigned* sorted  = (unsigned*)d_ws + (size_t)N_NODES * 128;  // 1.6M u32
    int*      bcnt    = (int*)(sorted + N_EDGES);            // NB
    int*      bbase   = bcnt + NB;                           // NB+1
    int*      bcursor = bbase + NB + 1;                      // NB

    hipMemsetAsync(bcnt, 0, NB * sizeof(int), stream);
    k_bhist<<<(N_EDGES + 2047) / 2048, 256, 0, stream>>>(dst, bcnt);
    k_bscan<<<1, 512, 0, stream>>>(bcnt, bbase, bcursor);
    k_bscatter<<<(N_EDGES + SC_CHUNK - 1) / SC_CHUNK, 256, 0, stream>>>(
        src, dst, etypes, bcursor, sorted);
    k_agg<<<NB, 512, 0, stream>>>(sorted, bbase, feat, w_comp, g_glob);
    k_post<<<1563, 192, 0, stream>>>(g_glob, feat, weight, loop_weight, h_bias, out);
}

// Round 5
// 307.567 us; speedup vs baseline: 5.2452x; 5.2452x over previous
//
#include <hip/hip_runtime.h>

// RelGraphConv basis-decomposition forward, MI355X.
//
// Input-space reformulation:
//   g[d, b, :] = sum_{e: dst_e = d} w_comp[et_e, b] * feat[src_e, :]   (b = 0,1)
//   out[d]     = g[d,0] @ V0 + g[d,1] @ V1 + feat[d] @ W_loop + bias
//
// Pipeline:
//   memset bcnt -> k_bhist (coarse 391-bucket hist, LDS-aggregated)
//   -> k_bscan (1-block scan of 391) -> k_bscatter (multisplit: contiguous
//   per-(block,bucket) runs) -> k_fine (per bucket: exact per-node CSR via
//   LDS hist+scan, writes land in a 16KB L2-resident window)
//   -> k_gather (wave per dst node, lane = feature: g accumulation)
//   -> k_post (dense [g0,g1,feat] (192) -> 64 GEMM + bias).

constexpr int N_NODES  = 100000;
constexpr int N_EDGES  = 1600000;
constexpr int IN_FEAT  = 64;
constexpr int OUT_FEAT = 64;

constexpr int BN = 256;                                // nodes per bucket
constexpr int NB = (N_NODES + BN - 1) / BN;            // 391 buckets
constexpr int SC_CHUNK = 4096;                         // edges per scatter block

// entry pack: dst_low(8) | src(17) | etype(6)
__device__ __forceinline__ unsigned pack_entry(int d, int s, int r) {
    return (unsigned)(d & (BN - 1)) | ((unsigned)s << 8) | ((unsigned)r << 25);
}

// ---------------------------------------------------------------- coarse hist
__global__ __launch_bounds__(256) void k_bhist(const int* __restrict__ dst,
                                               int* __restrict__ bcnt) {
    __shared__ int hist[NB];
    const int t = threadIdx.x;
    for (int i = t; i < NB; i += 256) hist[i] = 0;
    __syncthreads();
    const int cbase = blockIdx.x * 2048;
    #pragma unroll
    for (int k = 0; k < 8; ++k) {
        const int e = cbase + k * 256 + t;
        if (e < N_EDGES) atomicAdd(&hist[dst[e] >> 8], 1);
    }
    __syncthreads();
    for (int i = t; i < NB; i += 256)
        if (hist[i]) atomicAdd(&bcnt[i], hist[i]);
}

// ---------------------------------------------------------------- coarse scan
__global__ __launch_bounds__(512) void k_bscan(const int* __restrict__ bcnt,
                                               int* __restrict__ bbase,
                                               int* __restrict__ bcursor) {
    __shared__ int part[512];
    const int t = threadIdx.x;
    const int v = (t < NB) ? bcnt[t] : 0;
    part[t] = v;
    __syncthreads();
    for (int d = 1; d < 512; d <<= 1) {
        const int u = (t >= d) ? part[t - d] : 0;
        __syncthreads();
        part[t] += u;
        __syncthreads();
    }
    if (t < NB) {
        const int ex = part[t] - v;   // exclusive
        bbase[t] = ex;
        bcursor[t] = ex;
    }
    if (t == 0) bbase[NB] = N_EDGES;
}

// ---------------------------------------------------------------- multisplit
__global__ __launch_bounds__(256) void k_bscatter(const int* __restrict__ src,
                                                  const int* __restrict__ dst,
                                                  const int* __restrict__ et,
                                                  int* __restrict__ bcursor,
                                                  unsigned* __restrict__ sorted_c) {
    __shared__ int hist[NB], gb[NB], lcur[NB];
    const int t = threadIdx.x;
    const int cbase = blockIdx.x * SC_CHUNK;
    for (int i = t; i < NB; i += 256) { hist[i] = 0; lcur[i] = 0; }
    __syncthreads();
    #pragma unroll 1
    for (int k = 0; k < SC_CHUNK / 256; ++k) {
        const int e = cbase + k * 256 + t;
        if (e < N_EDGES) atomicAdd(&hist[dst[e] >> 8], 1);
    }
    __syncthreads();
    for (int i = t; i < NB; i += 256) {
        const int c = hist[i];
        gb[i] = c ? atomicAdd(&bcursor[i], c) : 0;
    }
    __syncthreads();
    #pragma unroll 1
    for (int k = 0; k < SC_CHUNK / 256; ++k) {
        const int e = cbase + k * 256 + t;
        if (e < N_EDGES) {
            const int d = dst[e];
            const int bkt = d >> 8;
            const int r = atomicAdd(&lcur[bkt], 1);
            sorted_c[gb[bkt] + r] = pack_entry(d, src[e], et[e]);
        }
    }
}

// ---------------------------------------------------------------- fine CSR
// One block per bucket: per-node counts + exclusive scan in LDS, write
// per-node offsets (coalesced) and reorder entries into exact CSR position
// (random 4B writes confined to this bucket's ~16KB window -> L2).
__global__ __launch_bounds__(256) void k_fine(const unsigned* __restrict__ sorted_c,
                                              const int* __restrict__ bbase,
                                              int* __restrict__ offsets,
                                              unsigned* __restrict__ sorted_f) {
    __shared__ int cnt[BN];
    __shared__ int part[BN];
    __shared__ int cur[BN];
    const int t = threadIdx.x;
    const int b = blockIdx.x;
    cnt[t] = 0;
    __syncthreads();
    const int base = bbase[b];
    const int end  = bbase[b + 1];
    for (int k = base + t; k < end; k += 256)
        atomicAdd(&cnt[sorted_c[k] & (BN - 1)], 1);
    __syncthreads();
    const int v = cnt[t];
    part[t] = v;
    __syncthreads();
    for (int d = 1; d < BN; d <<= 1) {
        const int u = (t >= d) ? part[t - d] : 0;
        __syncthreads();
        part[t] += u;
        __syncthreads();
    }
    const int node = b * BN + t;
    const int off = base + part[t] - v;   // exclusive within bucket
    if (node < N_NODES) offsets[node] = off;
    cur[t] = off;
    if (b == NB - 1 && t == 0) offsets[N_NODES] = N_EDGES;
    __syncthreads();
    for (int k = base + t; k < end; k += 256) {
        const unsigned en = sorted_c[k];
        const int pos = atomicAdd(&cur[en & (BN - 1)], 1);
        sorted_f[pos] = en;
    }
}

// ---------------------------------------------------------------- gather
// One 64-lane wave per dst node; lane = input feature. Edge entry + w_comp
// loads are wave-uniform (scalar path); feat row load is coalesced 256B.
__global__ __launch_bounds__(256) void k_gather(
    const int*      __restrict__ offsets,
    const unsigned* __restrict__ sorted_f,
    const float*    __restrict__ w_comp,   // (64, 2)
    const float*    __restrict__ feat,     // (N, 64)
    float*          __restrict__ g_glob)   // (N, 128): [0..63]=b0, [64..127]=b1
{
    const int lane = threadIdx.x & 63;
    int n = blockIdx.x * 4 + (threadIdx.x >> 6);
    if (n >= N_NODES) return;
    n = __builtin_amdgcn_readfirstlane(n);
    const int start = __builtin_amdgcn_readfirstlane(offsets[n]);
    const int end   = __builtin_amdgcn_readfirstlane(offsets[n + 1]);
    const float2* __restrict__ wc = (const float2*)w_comp;

    float a0 = 0.f, b0 = 0.f, a1 = 0.f, b1 = 0.f;
    int k = start;
    for (; k + 3 < end; k += 4) {
        const unsigned p0 = sorted_f[k],     p1 = sorted_f[k + 1];
        const unsigned p2 = sorted_f[k + 2], p3 = sorted_f[k + 3];
        const float f0 = feat[(size_t)((p0 >> 8) & 0x1FFFF) * 64 + lane];
        const float f1 = feat[(size_t)((p1 >> 8) & 0x1FFFF) * 64 + lane];
        const float f2 = feat[(size_t)((p2 >> 8) & 0x1FFFF) * 64 + lane];
        const float f3 = feat[(size_t)((p3 >> 8) & 0x1FFFF) * 64 + lane];
        const float2 c0 = wc[p0 >> 25], c1 = wc[p1 >> 25];
        const float2 c2 = wc[p2 >> 25], c3 = wc[p3 >> 25];
        a0 = fmaf(c0.x, f0, a0); b0 = fmaf(c0.y, f0, b0);
        a1 = fmaf(c1.x, f1, a1); b1 = fmaf(c1.y, f1, b1);
        a0 = fmaf(c2.x, f2, a0); b0 = fmaf(c2.y, f2, b0);
        a1 = fmaf(c3.x, f3, a1); b1 = fmaf(c3.y, f3, b1);
    }
    for (; k < end; ++k) {
        const unsigned p0 = sorted_f[k];
        const float f0 = feat[(size_t)((p0 >> 8) & 0x1FFFF) * 64 + lane];
        const float2 c0 = wc[p0 >> 25];
        a0 = fmaf(c0.x, f0, a0); b0 = fmaf(c0.y, f0, b0);
    }
    g_glob[(size_t)n * 128 + lane]      = a0 + a1;
    g_glob[(size_t)n * 128 + 64 + lane] = b0 + b1;
}

// ---------------------------------------------------------------- post GEMM
// out[n, col] = g0[n]@V0[:,col] + g1[n]@V1[:,col] + feat[n]@loop[:,col] + bias.
// 3 waves/block: wave seg owns one 64-dim K-segment, weight column in 64
// VGPRs; inputs staged per 8-node tile; partials combined via LDS.
__global__ __launch_bounds__(192) void k_post(
    const float* __restrict__ g_glob,      // (N, 128)
    const float* __restrict__ feat,        // (N, 64)
    const float* __restrict__ weight,      // (2, 64, 64)
    const float* __restrict__ loop_weight, // (64, 64)
    const float* __restrict__ h_bias,      // (64,)
    float* __restrict__ out)               // (N, 64)
{
    __shared__ float Lin[8][192];          // [node][0..127]=g, [128..191]=feat
    __shared__ float ps[3][8][64];
    const int tid = threadIdx.x;
    const int col = tid & 63;
    const int seg = tid >> 6;              // wave-uniform

    float wcol[64];
    #pragma unroll
    for (int i = 0; i < 64; ++i) {
        if (seg < 2) wcol[i] = weight[seg * (IN_FEAT * OUT_FEAT) + i * OUT_FEAT + col];
        else         wcol[i] = loop_weight[i * OUT_FEAT + col];
    }

    for (int base = blockIdx.x * 8; base < N_NODES; base += gridDim.x * 8) {
        __syncthreads();   // protect Lin + ps reuse
        for (int idx = tid; idx < 8 * 128; idx += 192) {
            const int j = idx >> 7, i = idx & 127, n = base + j;
            Lin[j][i] = (n < N_NODES) ? g_glob[(size_t)n * 128 + i] : 0.0f;
        }
        for (int idx = tid; idx < 8 * 64; idx += 192) {
            const int j = idx >> 6, i = idx & 63, n = base + j;
            Lin[j][128 + i] = (n < N_NODES) ? feat[(size_t)n * 64 + i] : 0.0f;
        }
        __syncthreads();
        #pragma unroll 1
        for (int j = 0; j < 8; ++j) {
            const float4* v4 = (const float4*)&Lin[j][seg * 64];
            float a0 = 0.f, a1 = 0.f, a2 = 0.f, a3 = 0.f;
            #pragma unroll
            for (int i4 = 0; i4 < 16; ++i4) {
                const float4 f = v4[i4];   // wave-uniform -> LDS broadcast
                a0 = fmaf(f.x, wcol[4 * i4 + 0], a0);
                a1 = fmaf(f.y, wcol[4 * i4 + 1], a1);
                a2 = fmaf(f.z, wcol[4 * i4 + 2], a2);
                a3 = fmaf(f.w, wcol[4 * i4 + 3], a3);
            }
            ps[seg][j][col] = (a0 + a1) + (a2 + a3);
        }
        __syncthreads();
        for (int o = tid; o < 512; o += 192) {
            const int j = o >> 6, c = o & 63, n = base + j;
            if (n < N_NODES)
                out[(size_t)n * 64 + c] = ps[0][j][c] + ps[1][j][c] + ps[2][j][c] + h_bias[c];
        }
    }
}

// ---------------------------------------------------------------- launch
extern "C" void kernel_launch(void* const* d_in, const int* in_sizes, int n_in,
                              void* d_out, int out_size, void* d_ws, size_t ws_size,
                              hipStream_t stream) {
    const float* feat        = (const float*)d_in[0];
    const float* weight      = (const float*)d_in[1];
    const float* w_comp      = (const float*)d_in[2];
    const float* loop_weight = (const float*)d_in[3];
    const float* h_bias      = (const float*)d_in[4];
    const int*   src         = (const int*)d_in[5];
    const int*   dst         = (const int*)d_in[6];
    const int*   etypes      = (const int*)d_in[7];
    float* out = (float*)d_out;

    // ws layout (4B units), ~58.0 MB total:
    //   g_glob (N*128 f32) -- its FIRST 1.6M units alias sorted_c, which is
    //   fully consumed by k_fine before k_gather writes g_glob.
    float*    g_glob   = (float*)d_ws;                        // 12.8M f32
    unsigned* sorted_c = (unsigned*)d_ws;                     // 1.6M u32 (alias)
    unsigned* sorted_f = (unsigned*)d_ws + (size_t)N_NODES * 128;  // 1.6M u32
    int*      offsets  = (int*)(sorted_f + N_EDGES);          // N+1
    int*      bcnt     = offsets + (N_NODES + 1);             // NB
    int*      bbase    = bcnt + NB;                           // NB+1
    int*      bcursor  = bbase + NB + 1;                      // NB

    hipMemsetAsync(bcnt, 0, NB * sizeof(int), stream);
    k_bhist<<<(N_EDGES + 2047) / 2048, 256, 0, stream>>>(dst, bcnt);
    k_bscan<<<1, 512, 0, stream>>>(bcnt, bbase, bcursor);
    k_bscatter<<<(N_EDGES + SC_CHUNK - 1) / SC_CHUNK, 256, 0, stream>>>(
        src, dst, etypes, bcursor, sorted_c);
    k_fine<<<NB, BN, 0, stream>>>(sorted_c, bbase, offsets, sorted_f);
    k_gather<<<(N_NODES + 3) / 4, 256, 0, stream>>>(offsets, sorted_f, w_comp, feat, g_glob);
    k_post<<<1563, 192, 0, stream>>>(g_glob, feat, weight, loop_weight, h_bias, out);
}

// Round 6
// 199.246 us; speedup vs baseline: 8.0967x; 1.5437x over previous
//
#include <hip/hip_runtime.h>

// RelGraphConv basis-decomposition forward, MI355X.
//
// Input-space reformulation:
//   g[d, b, :] = sum_{e: dst_e = d} w_comp[et_e, b] * feat[src_e, :]   (b = 0,1)
//   out[d]     = g[d,0] @ V0 + g[d,1] @ V1 + feat[d] @ W_loop + bias
//
// Pipeline:
//   memset bcnt -> k_bhist -> k_bscan -> k_bscatter (coarse 391-bucket
//   multisplit) -> k_fine (per-bucket exact per-node CSR in LDS)
//   -> k_gather_post (FUSED: per-wave edge gather into registers, then
//      in-block dense [g0,g1,feat](192) -> 64 GEMM; no g_glob round trip).

constexpr int N_NODES  = 100000;
constexpr int N_EDGES  = 1600000;
constexpr int IN_FEAT  = 64;
constexpr int OUT_FEAT = 64;

constexpr int BN = 256;                                // nodes per bucket
constexpr int NB = (N_NODES + BN - 1) / BN;            // 391 buckets
constexpr int SC_CHUNK = 4096;                         // edges per scatter block
constexpr int N_GROUPS = N_NODES / 4;                  // 25000 (exact)

// entry pack: dst_low(8) | src(17) | etype(6)
__device__ __forceinline__ unsigned pack_entry(int d, int s, int r) {
    return (unsigned)(d & (BN - 1)) | ((unsigned)s << 8) | ((unsigned)r << 25);
}

// ---------------------------------------------------------------- coarse hist
__global__ __launch_bounds__(256) void k_bhist(const int* __restrict__ dst,
                                               int* __restrict__ bcnt) {
    __shared__ int hist[NB];
    const int t = threadIdx.x;
    for (int i = t; i < NB; i += 256) hist[i] = 0;
    __syncthreads();
    const int cbase = blockIdx.x * 2048;
    #pragma unroll
    for (int k = 0; k < 8; ++k) {
        const int e = cbase + k * 256 + t;
        if (e < N_EDGES) atomicAdd(&hist[dst[e] >> 8], 1);
    }
    __syncthreads();
    for (int i = t; i < NB; i += 256)
        if (hist[i]) atomicAdd(&bcnt[i], hist[i]);
}

// ---------------------------------------------------------------- coarse scan
__global__ __launch_bounds__(512) void k_bscan(const int* __restrict__ bcnt,
                                               int* __restrict__ bbase,
                                               int* __restrict__ bcursor) {
    __shared__ int part[512];
    const int t = threadIdx.x;
    const int v = (t < NB) ? bcnt[t] : 0;
    part[t] = v;
    __syncthreads();
    for (int d = 1; d < 512; d <<= 1) {
        const int u = (t >= d) ? part[t - d] : 0;
        __syncthreads();
        part[t] += u;
        __syncthreads();
    }
    if (t < NB) {
        const int ex = part[t] - v;   // exclusive
        bbase[t] = ex;
        bcursor[t] = ex;
    }
    if (t == 0) bbase[NB] = N_EDGES;
}

// ---------------------------------------------------------------- multisplit
__global__ __launch_bounds__(256) void k_bscatter(const int* __restrict__ src,
                                                  const int* __restrict__ dst,
                                                  const int* __restrict__ et,
                                                  int* __restrict__ bcursor,
                                                  unsigned* __restrict__ sorted_c) {
    __shared__ int hist[NB], gb[NB], lcur[NB];
    const int t = threadIdx.x;
    const int cbase = blockIdx.x * SC_CHUNK;
    for (int i = t; i < NB; i += 256) { hist[i] = 0; lcur[i] = 0; }
    __syncthreads();
    #pragma unroll 1
    for (int k = 0; k < SC_CHUNK / 256; ++k) {
        const int e = cbase + k * 256 + t;
        if (e < N_EDGES) atomicAdd(&hist[dst[e] >> 8], 1);
    }
    __syncthreads();
    for (int i = t; i < NB; i += 256) {
        const int c = hist[i];
        gb[i] = c ? atomicAdd(&bcursor[i], c) : 0;
    }
    __syncthreads();
    #pragma unroll 1
    for (int k = 0; k < SC_CHUNK / 256; ++k) {
        const int e = cbase + k * 256 + t;
        if (e < N_EDGES) {
            const int d = dst[e];
            const int bkt = d >> 8;
            const int r = atomicAdd(&lcur[bkt], 1);
            sorted_c[gb[bkt] + r] = pack_entry(d, src[e], et[e]);
        }
    }
}

// ---------------------------------------------------------------- fine CSR
__global__ __launch_bounds__(256) void k_fine(const unsigned* __restrict__ sorted_c,
                                              const int* __restrict__ bbase,
                                              int* __restrict__ offsets,
                                              unsigned* __restrict__ sorted_f) {
    __shared__ int cnt[BN];
    __shared__ int part[BN];
    __shared__ int cur[BN];
    const int t = threadIdx.x;
    const int b = blockIdx.x;
    cnt[t] = 0;
    __syncthreads();
    const int base = bbase[b];
    const int end  = bbase[b + 1];
    for (int k = base + t; k < end; k += 256)
        atomicAdd(&cnt[sorted_c[k] & (BN - 1)], 1);
    __syncthreads();
    const int v = cnt[t];
    part[t] = v;
    __syncthreads();
    for (int d = 1; d < BN; d <<= 1) {
        const int u = (t >= d) ? part[t - d] : 0;
        __syncthreads();
        part[t] += u;
        __syncthreads();
    }
    const int node = b * BN + t;
    const int off = base + part[t] - v;   // exclusive within bucket
    if (node < N_NODES) offsets[node] = off;
    cur[t] = off;
    if (b == NB - 1 && t == 0) offsets[N_NODES] = N_EDGES;
    __syncthreads();
    for (int k = base + t; k < end; k += 256) {
        const unsigned en = sorted_c[k];
        const int pos = atomicAdd(&cur[en & (BN - 1)], 1);
        sorted_f[pos] = en;
    }
}

// ---------------------------------------------------------------- fused
// 256 threads = 4 waves. Grid-strided over 4-node groups.
// Phase 1 (wave w = node grp*4+w): register gather of g0,g1 + feat row.
// Phase 2 (thread = (col, seg)): out[nj, col] += sum over K-segment seg*48..+48
//   of Lin[nj][k] * Wcat[k][col], Wcat = [V0; V1; W_loop] held in 48 VGPRs.
__global__ __launch_bounds__(256, 4) void k_gather_post(
    const int*      __restrict__ offsets,
    const unsigned* __restrict__ sorted_f,
    const float*    __restrict__ w_comp,      // (64, 2)
    const float*    __restrict__ feat,        // (N, 64)
    const float*    __restrict__ weight,      // (2, 64, 64)
    const float*    __restrict__ loop_weight, // (64, 64)
    const float*    __restrict__ h_bias,      // (64,)
    float*          __restrict__ out)         // (N, 64)
{
    __shared__ float4 Lin4[4][48];            // [node][192 floats]: g0|g1|feat
    __shared__ float  ps[4][4][64];           // [seg][node][col]
    float* Lin = (float*)Lin4;

    const int tid  = threadIdx.x;
    const int lane = tid & 63;                // = col in phase 2
    const int w    = tid >> 6;                // wave = node slot = K-seg
    const int kbase = w * 48;

    // Wcat column segment in VGPRs (once per block, reused over ~12 groups).
    float wcol[48];
    #pragma unroll
    for (int i = 0; i < 48; ++i) {
        const int r = kbase + i;
        wcol[i] = (r < 64)  ? weight[r * 64 + lane]
                : (r < 128) ? weight[64 * 64 + (r - 64) * 64 + lane]
                            : loop_weight[(r - 128) * 64 + lane];
    }
    const float bias = h_bias[lane];
    const float2* __restrict__ wc = (const float2*)w_comp;

    for (int grp = blockIdx.x; grp < N_GROUPS; grp += gridDim.x) {
        const int n = __builtin_amdgcn_readfirstlane(grp * 4 + w);  // < N_NODES always
        const int start = __builtin_amdgcn_readfirstlane(offsets[n]);
        const int end   = __builtin_amdgcn_readfirstlane(offsets[n + 1]);

        float a0 = 0.f, b0 = 0.f, a1 = 0.f, b1 = 0.f;
        int k = start;
        for (; k + 3 < end; k += 4) {
            const unsigned p0 = sorted_f[k],     p1 = sorted_f[k + 1];
            const unsigned p2 = sorted_f[k + 2], p3 = sorted_f[k + 3];
            const float f0 = feat[(size_t)((p0 >> 8) & 0x1FFFF) * 64 + lane];
            const float f1 = feat[(size_t)((p1 >> 8) & 0x1FFFF) * 64 + lane];
            const float f2 = feat[(size_t)((p2 >> 8) & 0x1FFFF) * 64 + lane];
            const float f3 = feat[(size_t)((p3 >> 8) & 0x1FFFF) * 64 + lane];
            const float2 c0 = wc[p0 >> 25], c1 = wc[p1 >> 25];
            const float2 c2 = wc[p2 >> 25], c3 = wc[p3 >> 25];
            a0 = fmaf(c0.x, f0, a0); b0 = fmaf(c0.y, f0, b0);
            a1 = fmaf(c1.x, f1, a1); b1 = fmaf(c1.y, f1, b1);
            a0 = fmaf(c2.x, f2, a0); b0 = fmaf(c2.y, f2, b0);
            a1 = fmaf(c3.x, f3, a1); b1 = fmaf(c3.y, f3, b1);
        }
        for (; k < end; ++k) {
            const unsigned p0 = sorted_f[k];
            const float f0 = feat[(size_t)((p0 >> 8) & 0x1FFFF) * 64 + lane];
            const float2 c0 = wc[p0 >> 25];
            a0 = fmaf(c0.x, f0, a0); b0 = fmaf(c0.y, f0, b0);
        }
        const float fv = feat[(size_t)n * 64 + lane];

        __syncthreads();   // prior iteration's Lin reads complete
        Lin[w * 192 + lane]       = a0 + a1;
        Lin[w * 192 + 64 + lane]  = b0 + b1;
        Lin[w * 192 + 128 + lane] = fv;
        __syncthreads();

        // Phase 2: each thread covers K-segment [kbase, kbase+48) for 4 nodes.
        #pragma unroll
        for (int j = 0; j < 4; ++j) {
            const float4* v4 = (const float4*)&Lin4[0][0] + j * 48 + (kbase >> 2);
            float p0 = 0.f, p1 = 0.f;
            #pragma unroll
            for (int i4 = 0; i4 < 12; i4 += 2) {
                const float4 x = v4[i4];       // uniform -> LDS broadcast
                const float4 y = v4[i4 + 1];
                p0 = fmaf(x.x, wcol[4 * i4 + 0], p0);
                p0 = fmaf(x.y, wcol[4 * i4 + 1], p0);
                p0 = fmaf(x.z, wcol[4 * i4 + 2], p0);
                p0 = fmaf(x.w, wcol[4 * i4 + 3], p0);
                p1 = fmaf(y.x, wcol[4 * i4 + 4], p1);
                p1 = fmaf(y.y, wcol[4 * i4 + 5], p1);
                p1 = fmaf(y.z, wcol[4 * i4 + 6], p1);
                p1 = fmaf(y.w, wcol[4 * i4 + 7], p1);
            }
            ps[w][j][lane] = p0 + p1;
        }
        __syncthreads();

        // One output per thread: node slot = w, col = lane. Coalesced.
        out[(size_t)(grp * 4 + w) * 64 + lane] =
            ps[0][w][lane] + ps[1][w][lane] + ps[2][w][lane] + ps[3][w][lane] + bias;
    }
}

// ---------------------------------------------------------------- launch
extern "C" void kernel_launch(void* const* d_in, const int* in_sizes, int n_in,
                              void* d_out, int out_size, void* d_ws, size_t ws_size,
                              hipStream_t stream) {
    const float* feat        = (const float*)d_in[0];
    const float* weight      = (const float*)d_in[1];
    const float* w_comp      = (const float*)d_in[2];
    const float* loop_weight = (const float*)d_in[3];
    const float* h_bias      = (const float*)d_in[4];
    const int*   src         = (const int*)d_in[5];
    const int*   dst         = (const int*)d_in[6];
    const int*   etypes      = (const int*)d_in[7];
    float* out = (float*)d_out;

    // ws layout (4B units), ~13.2 MB total, no aliasing:
    unsigned* sorted_c = (unsigned*)d_ws;                     // 1.6M u32
    unsigned* sorted_f = sorted_c + N_EDGES;                  // 1.6M u32
    int*      offsets  = (int*)(sorted_f + N_EDGES);          // N+1
    int*      bcnt     = offsets + (N_NODES + 1);             // NB
    int*      bbase    = bcnt + NB;                           // NB+1
    int*      bcursor  = bbase + NB + 1;                      // NB

    hipMemsetAsync(bcnt, 0, NB * sizeof(int), stream);
    k_bhist<<<(N_EDGES + 2047) / 2048, 256, 0, stream>>>(dst, bcnt);
    k_bscan<<<1, 512, 0, stream>>>(bcnt, bbase, bcursor);
    k_bscatter<<<(N_EDGES + SC_CHUNK - 1) / SC_CHUNK, 256, 0, stream>>>(
        src, dst, etypes, bcursor, sorted_c);
    k_fine<<<NB, BN, 0, stream>>>(sorted_c, bbase, offsets, sorted_f);
    k_gather_post<<<2048, 256, 0, stream>>>(offsets, sorted_f, w_comp, feat,
                                            weight, loop_weight, h_bias, out);
}

// Round 7
// 164.852 us; speedup vs baseline: 9.7860x; 1.2086x over previous
//
#include <hip/hip_runtime.h>

// RelGraphConv basis-decomposition forward, MI355X.
//
// Input-space reformulation:
//   g[d, b, :] = sum_{e: dst_e = d} w_comp[et_e, b] * feat[src_e, :]   (b = 0,1)
//   out[d]     = g[d,0] @ V0 + g[d,1] @ V1 + feat[d] @ W_loop + bias
//
// Pipeline:
//   memset bcnt -> k_bhist -> k_bscan -> k_bscatter (coarse 391-bucket
//   multisplit) -> k_fine (per-bucket exact per-node CSR in LDS)
//   -> k_gather_post (FUSED: per-wave register gather of TWO nodes (8-deep
//      unroll, 8 loads in flight), then in-block dense [g0,g1,feat](192)->64
//      GEMM over 8 nodes per barrier-pair).

constexpr int N_NODES  = 100000;
constexpr int N_EDGES  = 1600000;
constexpr int IN_FEAT  = 64;
constexpr int OUT_FEAT = 64;

constexpr int BN = 256;                                // nodes per bucket
constexpr int NB = (N_NODES + BN - 1) / BN;            // 391 buckets
constexpr int SC_CHUNK = 4096;                         // edges per scatter block

constexpr int NODES_PER_GRP = 8;
constexpr int N_GRP  = N_NODES / NODES_PER_GRP;        // 12500 (exact)
constexpr int GP_GRID = 2500;                          // 5 groups per block, exact

// entry pack: dst_low(8) | src(17) | etype(6)
__device__ __forceinline__ unsigned pack_entry(int d, int s, int r) {
    return (unsigned)(d & (BN - 1)) | ((unsigned)s << 8) | ((unsigned)r << 25);
}

// ---------------------------------------------------------------- coarse hist
__global__ __launch_bounds__(256) void k_bhist(const int* __restrict__ dst,
                                               int* __restrict__ bcnt) {
    __shared__ int hist[NB];
    const int t = threadIdx.x;
    for (int i = t; i < NB; i += 256) hist[i] = 0;
    __syncthreads();
    const int cbase = blockIdx.x * 2048;
    #pragma unroll
    for (int k = 0; k < 8; ++k) {
        const int e = cbase + k * 256 + t;
        if (e < N_EDGES) atomicAdd(&hist[dst[e] >> 8], 1);
    }
    __syncthreads();
    for (int i = t; i < NB; i += 256)
        if (hist[i]) atomicAdd(&bcnt[i], hist[i]);
}

// ---------------------------------------------------------------- coarse scan
__global__ __launch_bounds__(512) void k_bscan(const int* __restrict__ bcnt,
                                               int* __restrict__ bbase,
                                               int* __restrict__ bcursor) {
    __shared__ int part[512];
    const int t = threadIdx.x;
    const int v = (t < NB) ? bcnt[t] : 0;
    part[t] = v;
    __syncthreads();
    for (int d = 1; d < 512; d <<= 1) {
        const int u = (t >= d) ? part[t - d] : 0;
        __syncthreads();
        part[t] += u;
        __syncthreads();
    }
    if (t < NB) {
        const int ex = part[t] - v;   // exclusive
        bbase[t] = ex;
        bcursor[t] = ex;
    }
    if (t == 0) bbase[NB] = N_EDGES;
}

// ---------------------------------------------------------------- multisplit
__global__ __launch_bounds__(256) void k_bscatter(const int* __restrict__ src,
                                                  const int* __restrict__ dst,
                                                  const int* __restrict__ et,
                                                  int* __restrict__ bcursor,
                                                  unsigned* __restrict__ sorted_c) {
    __shared__ int hist[NB], gb[NB], lcur[NB];
    const int t = threadIdx.x;
    const int cbase = blockIdx.x * SC_CHUNK;
    for (int i = t; i < NB; i += 256) { hist[i] = 0; lcur[i] = 0; }
    __syncthreads();
    #pragma unroll 1
    for (int k = 0; k < SC_CHUNK / 256; ++k) {
        const int e = cbase + k * 256 + t;
        if (e < N_EDGES) atomicAdd(&hist[dst[e] >> 8], 1);
    }
    __syncthreads();
    for (int i = t; i < NB; i += 256) {
        const int c = hist[i];
        gb[i] = c ? atomicAdd(&bcursor[i], c) : 0;
    }
    __syncthreads();
    #pragma unroll 1
    for (int k = 0; k < SC_CHUNK / 256; ++k) {
        const int e = cbase + k * 256 + t;
        if (e < N_EDGES) {
            const int d = dst[e];
            const int bkt = d >> 8;
            const int r = atomicAdd(&lcur[bkt], 1);
            sorted_c[gb[bkt] + r] = pack_entry(d, src[e], et[e]);
        }
    }
}

// ---------------------------------------------------------------- fine CSR
__global__ __launch_bounds__(256) void k_fine(const unsigned* __restrict__ sorted_c,
                                              const int* __restrict__ bbase,
                                              int* __restrict__ offsets,
                                              unsigned* __restrict__ sorted_f) {
    __shared__ int cnt[BN];
    __shared__ int part[BN];
    __shared__ int cur[BN];
    const int t = threadIdx.x;
    const int b = blockIdx.x;
    cnt[t] = 0;
    __syncthreads();
    const int base = bbase[b];
    const int end  = bbase[b + 1];
    for (int k = base + t; k < end; k += 256)
        atomicAdd(&cnt[sorted_c[k] & (BN - 1)], 1);
    __syncthreads();
    const int v = cnt[t];
    part[t] = v;
    __syncthreads();
    for (int d = 1; d < BN; d <<= 1) {
        const int u = (t >= d) ? part[t - d] : 0;
        __syncthreads();
        part[t] += u;
        __syncthreads();
    }
    const int node = b * BN + t;
    const int off = base + part[t] - v;   // exclusive within bucket
    if (node < N_NODES) offsets[node] = off;
    cur[t] = off;
    if (b == NB - 1 && t == 0) offsets[N_NODES] = N_EDGES;
    __syncthreads();
    for (int k = base + t; k < end; k += 256) {
        const unsigned en = sorted_c[k];
        const int pos = atomicAdd(&cur[en & (BN - 1)], 1);
        sorted_f[pos] = en;
    }
}

// ---------------------------------------------------------------- fused
// 256 threads = 4 waves; 2500 blocks x exactly 5 groups of 8 nodes.
// Phase 1: wave w register-gathers nodes grp*8+w and grp*8+4+w (8-deep
//          unroll -> 8 gathers in flight) and stores [g0|g1|feat] to LDS.
// Phase 2: thread (seg=w, col=lane) does the 48-row K-segment of the
//          192->64 GEMM for all 8 nodes; LDS partial reduce; coalesced out.
__global__ __launch_bounds__(256, 4) void k_gather_post(
    const int*      __restrict__ offsets,
    const unsigned* __restrict__ sorted_f,
    const float*    __restrict__ w_comp,      // (64, 2)
    const float*    __restrict__ feat,        // (N, 64)
    const float*    __restrict__ weight,      // (2, 64, 64)
    const float*    __restrict__ loop_weight, // (64, 64)
    const float*    __restrict__ h_bias,      // (64,)
    float*          __restrict__ out)         // (N, 64)
{
    __shared__ float4 Lin4[NODES_PER_GRP][48];  // [node][192 f32]: g0|g1|feat
    __shared__ float  ps[4][NODES_PER_GRP][64]; // [seg][node][col]
    float* Lin = (float*)Lin4;

    const int tid  = threadIdx.x;
    const int lane = tid & 63;                // = col in phase 2
    const int w    = tid >> 6;                // wave = K-seg in phase 2

    // Wcat (= [V0; V1; W_loop]) column segment, rows w*48..w*48+47.
    float wcol[48];
    #pragma unroll
    for (int i = 0; i < 48; ++i) {
        const int r = w * 48 + i;
        wcol[i] = (r < 64)  ? weight[r * 64 + lane]
                : (r < 128) ? weight[64 * 64 + (r - 64) * 64 + lane]
                            : loop_weight[(r - 128) * 64 + lane];
    }
    const float bias = h_bias[lane];
    const float2* __restrict__ wc = (const float2*)w_comp;

    #pragma unroll 1
    for (int g = 0; g < N_GRP / GP_GRID; ++g) {
        const int grp = blockIdx.x + g * GP_GRID;

        __syncthreads();   // prior iteration's ps reads complete; Lin free

        // ---- Phase 1: gather 2 nodes per wave ----
        #pragma unroll 1
        for (int half = 0; half < 2; ++half) {
            const int n = __builtin_amdgcn_readfirstlane(grp * 8 + half * 4 + w);
            const int start = __builtin_amdgcn_readfirstlane(offsets[n]);
            const int end   = __builtin_amdgcn_readfirstlane(offsets[n + 1]);
            const float fv = feat[(size_t)n * 64 + lane];

            float a0 = 0.f, b0 = 0.f, a1 = 0.f, b1 = 0.f;
            int k = start;
            for (; k + 7 < end; k += 8) {
                unsigned p[8]; float f[8];
                #pragma unroll
                for (int i = 0; i < 8; ++i) p[i] = sorted_f[k + i];   // uniform -> s_load
                #pragma unroll
                for (int i = 0; i < 8; ++i)
                    f[i] = feat[(size_t)((p[i] >> 8) & 0x1FFFF) * 64 + lane];
                #pragma unroll
                for (int i = 0; i < 8; ++i) {
                    const float2 c = wc[p[i] >> 25];
                    if (i & 1) { a1 = fmaf(c.x, f[i], a1); b1 = fmaf(c.y, f[i], b1); }
                    else       { a0 = fmaf(c.x, f[i], a0); b0 = fmaf(c.y, f[i], b0); }
                }
            }
            for (; k + 3 < end; k += 4) {
                unsigned p[4]; float f[4];
                #pragma unroll
                for (int i = 0; i < 4; ++i) p[i] = sorted_f[k + i];
                #pragma unroll
                for (int i = 0; i < 4; ++i)
                    f[i] = feat[(size_t)((p[i] >> 8) & 0x1FFFF) * 64 + lane];
                #pragma unroll
                for (int i = 0; i < 4; ++i) {
                    const float2 c = wc[p[i] >> 25];
                    if (i & 1) { a1 = fmaf(c.x, f[i], a1); b1 = fmaf(c.y, f[i], b1); }
                    else       { a0 = fmaf(c.x, f[i], a0); b0 = fmaf(c.y, f[i], b0); }
                }
            }
            for (; k < end; ++k) {
                const unsigned p0 = sorted_f[k];
                const float f0 = feat[(size_t)((p0 >> 8) & 0x1FFFF) * 64 + lane];
                const float2 c0 = wc[p0 >> 25];
                a0 = fmaf(c0.x, f0, a0); b0 = fmaf(c0.y, f0, b0);
            }
            const int slot = half * 4 + w;
            Lin[slot * 192 + lane]       = a0 + a1;
            Lin[slot * 192 + 64 + lane]  = b0 + b1;
            Lin[slot * 192 + 128 + lane] = fv;
        }
        __syncthreads();

        // ---- Phase 2: K-segment GEMM over 8 nodes ----
        #pragma unroll
        for (int j = 0; j < NODES_PER_GRP; ++j) {
            const float4* v4 = (const float4*)&Lin4[0][0] + j * 48 + w * 12;
            float p0 = 0.f, p1 = 0.f;
            #pragma unroll
            for (int i4 = 0; i4 < 12; i4 += 2) {
                const float4 x = v4[i4];       // uniform -> LDS broadcast
                const float4 y = v4[i4 + 1];
                p0 = fmaf(x.x, wcol[4 * i4 + 0], p0);
                p0 = fmaf(x.y, wcol[4 * i4 + 1], p0);
                p0 = fmaf(x.z, wcol[4 * i4 + 2], p0);
                p0 = fmaf(x.w, wcol[4 * i4 + 3], p0);
                p1 = fmaf(y.x, wcol[4 * i4 + 4], p1);
                p1 = fmaf(y.y, wcol[4 * i4 + 5], p1);
                p1 = fmaf(y.z, wcol[4 * i4 + 6], p1);
                p1 = fmaf(y.w, wcol[4 * i4 + 7], p1);
            }
            ps[w][j][lane] = p0 + p1;
        }
        __syncthreads();

        // Two outputs per thread: node slots w and w+4. Coalesced.
        #pragma unroll
        for (int half = 0; half < 2; ++half) {
            const int slot = half * 4 + w;
            out[(size_t)(grp * 8 + slot) * 64 + lane] =
                ps[0][slot][lane] + ps[1][slot][lane] +
                ps[2][slot][lane] + ps[3][slot][lane] + bias;
        }
    }
}

// ---------------------------------------------------------------- launch
extern "C" void kernel_launch(void* const* d_in, const int* in_sizes, int n_in,
                              void* d_out, int out_size, void* d_ws, size_t ws_size,
                              hipStream_t stream) {
    const float* feat        = (const float*)d_in[0];
    const float* weight      = (const float*)d_in[1];
    const float* w_comp      = (const float*)d_in[2];
    const float* loop_weight = (const float*)d_in[3];
    const float* h_bias      = (const float*)d_in[4];
    const int*   src         = (const int*)d_in[5];
    const int*   dst         = (const int*)d_in[6];
    const int*   etypes     = (const int*)d_in[7];
    float* out = (float*)d_out;

    // ws layout (4B units), ~13.2 MB total, no aliasing:
    unsigned* sorted_c = (unsigned*)d_ws;                     // 1.6M u32
    unsigned* sorted_f = sorted_c + N_EDGES;                  // 1.6M u32
    int*      offsets  = (int*)(sorted_f + N_EDGES);          // N+1
    int*      bcnt     = offsets + (N_NODES + 1);             // NB
    int*      bbase    = bcnt + NB;                           // NB+1
    int*      bcursor  = bbase + NB + 1;                      // NB

    hipMemsetAsync(bcnt, 0, NB * sizeof(int), stream);
    k_bhist<<<(N_EDGES + 2047) / 2048, 256, 0, stream>>>(dst, bcnt);
    k_bscan<<<1, 512, 0, stream>>>(bcnt, bbase, bcursor);
    k_bscatter<<<(N_EDGES + SC_CHUNK - 1) / SC_CHUNK, 256, 0, stream>>>(
        src, dst, etypes, bcursor, sorted_c);
    k_fine<<<NB, BN, 0, stream>>>(sorted_c, bbase, offsets, sorted_f);
    k_gather_post<<<GP_GRID, 256, 0, stream>>>(offsets, sorted_f, w_comp, feat,
                                               weight, loop_weight, h_bias, out);
}